// Round 4
// baseline (143.146 us; speedup 1.0000x reference)
//
#include <hip/hip_runtime.h>

#define NIMG 4
#define NCLS 19
#define CCH  32
#define LH   128
#define LW   128
#define HH   512
#define WW   512
#define HWQ  (LH*LW)    // 16384 low-res pixels
#define HWP  (HH*WW)    // 262144 hi-res pixels

// k_field tiling: each block OWNS a disjoint TRxTC low-res region
#define TR 8
#define TC 8
#define NTX (LW/TC)       // 16
#define NTILE (256)       // tiles per image -> 1024 blocks total
#define TCELLS (TR*TC)    // 64
#define RW 10             // ring width  (X0-1 .. X0+8)
#define RING 100          // ring cells 10x10 (Y0-1 .. Y0+8)
#define NSLOT 608         // NCLS*CCH

// Bilinear taps for 128 -> 512, half-pixel convention. Edge taps shifted to a
// valid (b, b+1) pair with weights {1,0}/{0,1} (exact dyadic, same math).
__device__ __forceinline__ void taps(int v, int lim, int& i0, float& w0, float& w1) {
    int r = v & 3;
    int b = (v >> 2) + ((r < 2) ? -1 : 0);
    float f = 0.125f + 0.25f * (float)((r + 2) & 3);   // r: 0->.625 1->.875 2->.125 3->.375
    w0 = 1.f - f; w1 = f;
    if (b < 0)           { b = 0;       w0 = 1.f; w1 = 0.f; }
    else if (b >= lim)   { b = lim - 1; w0 = 0.f; w1 = 1.f; }
    i0 = b;
}

__device__ __forceinline__ float ring_fetch(const float* Gn, int i, int Y0, int X0) {
    int p = i / RING, r = i - p * RING;
    int gy = r / RW, gx = r - gy * RW;
    int yy = Y0 - 1 + gy; yy = yy < 0 ? 0 : (yy > LH - 1 ? LH - 1 : yy);
    int xx = X0 - 1 + gx; xx = xx < 0 ? 0 : (xx > LW - 1 ? LW - 1 : xx);
    return Gn[(size_t)p * HWQ + yy * LW + xx];
}

// K0: pre-summed Gram planes (over all 32 ch):
//   G[n][0]=<E,E>  G[n][1]=<E(y,x),E(y,x+1)>  G[n][2]=<E(y,x),E(y+1,x)>
//   G[n][3]=<E(y,x),E(y+1,x+1)> + <E(y,x+1),E(y+1,x)>
// Block (0,0) also zeroes AccCS (visible to k_field via kernel-boundary flush).
__global__ __launch_bounds__(256) void k_gram(const float* __restrict__ E,
        float* __restrict__ G, float* __restrict__ AccCS) {
    int n = blockIdx.y, rp = blockIdx.x;
    int tid = threadIdx.x;
    if (n == 0 && rp == 0 && tid < NIMG * 2 * NCLS) AccCS[tid] = 0.f;
    int x = tid & 127, dy = tid >> 7;
    int y = rp * 2 + dy;
    int yn = (y < LH - 1) ? y + 1 : y;
    int xn = (x < LW - 1) ? x + 1 : x;
    bool fix = ((x & 63) == 63);             // wave edge: shfl_down(1) invalid
    const float* base = E + (size_t)n * CCH * HWQ;
    const float* Ea = base + y * LW + x;
    const float* Eb = base + yn * LW + x;
    const float* Eax = base + y * LW + xn;
    const float* Ebx = base + yn * LW + xn;
    float gs = 0.f, gh = 0.f, gv = 0.f, gda = 0.f;
#pragma unroll 8
    for (int c = 0; c < CCH; c++) {
        float a = Ea[(size_t)c * HWQ];
        float b = Eb[(size_t)c * HWQ];
        float ar = __shfl_down(a, 1);
        float br = __shfl_down(b, 1);
        if (fix) { ar = Eax[(size_t)c * HWQ]; br = Ebx[(size_t)c * HWQ]; }
        gs = fmaf(a, a, gs);
        gh = fmaf(a, ar, gh);
        gv = fmaf(a, b, gv);
        gda = fmaf(a, br, fmaf(ar, b, gda));
    }
    float* Gp = G + (size_t)n * 4 * HWQ + y * LW + x;
    Gp[0] = gs; Gp[HWQ] = gh; Gp[2 * HWQ] = gv; Gp[3 * HWQ] = gda;
}

// K1: ring-stage Gram, quad-row halo pass (A-field + per-pixel S2 via Gram),
// contract with in-wave reduce -> transposed plain stores. cnt/S2 via tiny
// global f32 atomics (exact dyadic / small).
__global__ __launch_bounds__(256, 4) void k_field(const float* __restrict__ E,
        const int* __restrict__ lab, const float* __restrict__ G,
        float* __restrict__ P_sumT, float* __restrict__ AccCS) {
    int tile = blockIdx.x, n = blockIdx.y;
    int ty = tile >> 4, tx = tile & 15;         // NTX=16
    int Y0 = ty * TR, X0 = tx * TC;
    __shared__ float A[TCELLS * NCLS];          // 4864 B [cell][k]
    __shared__ float Gt[4 * RING];              // 1600 B Gs,Gh,Gv,Gda ring
    __shared__ float S2w[4 * NCLS];             // per-wave S2 accumulators
    __shared__ float tmpc[NCLS * 8];            // cnt partials
    int tid = threadIdx.x;
    const int* ln = lab + (size_t)n * HWP;
    int h_lo = Y0 * 4 - 2;

    // ---- hoist all cold global loads: 2x lab int4, 2x E float4, 2x G ring ----
    int hA, qA, hB = 0, qB = 0; bool vB;
    int4 LA, LB = make_int4(0, 0, 0, 0);
    {
        int hr = tid / RW, qi = tid - hr * RW;
        hA = h_lo + hr; qA = X0 - 1 + qi;
        int hc = hA < 0 ? 0 : (hA > HH - 1 ? HH - 1 : hA);
        int qc = qA < 0 ? 0 : (qA > LW - 1 ? LW - 1 : qA);
        LA = *(const int4*)(ln + hc * WW + (qc << 2));
    }
    vB = (tid < 360 - 256);
    if (vB) {
        int i = tid + 256;
        int hr = i / RW, qi = i - hr * RW;
        hB = h_lo + hr; qB = X0 - 1 + qi;
        int hc = hB < 0 ? 0 : (hB > HH - 1 ? HH - 1 : hB);
        int qc = qB < 0 ? 0 : (qB > LW - 1 ? LW - 1 : qB);
        LB = *(const int4*)(ln + hc * WW + (qc << 2));
    }
    int cc = tid >> 3, cy = tid & 7;
    const float* Er = E + ((size_t)n * CCH + cc) * HWQ + (Y0 + cy) * LW + X0;
    float4 ev0 = *(const float4*)Er;
    float4 ev1 = *(const float4*)(Er + 4);
    const float* Gn = G + (size_t)n * 4 * HWQ;
    float rv0 = ring_fetch(Gn, tid, Y0, X0);
    bool rB = (tid < 4 * RING - 256);
    float rv1 = rB ? ring_fetch(Gn, tid + 256, Y0, X0) : 0.f;

    // ---- LDS init + ring write ----
    for (int i = tid; i < TCELLS * NCLS; i += 256) A[i] = 0.f;
    if (tid < 4 * NCLS) S2w[tid] = 0.f;
    Gt[tid] = rv0;
    if (rB) Gt[tid + 256] = rv1;
    __syncthreads();

    // ---- halo pass: one thread per 4-pixel quad-row (2 hoisted iterations) ----
    const float* Gs_ = Gt, *Gh_ = Gt + RING, *Gv_ = Gt + 2 * RING, *Gda_ = Gt + 3 * RING;
    auto process = [&](int h, int q, int4 l4) {
        if (h < 0 || h >= HH || q < 0 || q >= LW) return;
        int y0; float wy0, wy1;
        taps(h, LH - 1, y0, wy0, wy1);
        int ry = y0 - Y0;
        bool r0 = (unsigned)ry < (unsigned)TR, r1 = (unsigned)(ry + 1) < (unsigned)TR;
        int rxm = q - 1 - X0, rx0 = q - X0, rxp = q + 1 - X0;
        bool bm = (unsigned)rxm < (unsigned)TC, b0 = (unsigned)rx0 < (unsigned)TC,
             bp = (unsigned)rxp < (unsigned)TC;
        bool fast = (q >= 1) && (q <= 126);
        bool owned = ((unsigned)(h - Y0 * 4) < 32u) && b0;
        if (fast) {
            // x-weights: p0:(q-1:.375,q:.625) p1:(.125,.875) p2:(q:.875,q+1:.125) p3:(.625,.375)
            if (r0) {
                int rb = (ry * TC) * NCLS;
                if (bm) { float* a = &A[rb + rxm * NCLS];
                    atomicAdd(a + l4.x, wy0 * 0.375f); atomicAdd(a + l4.y, wy0 * 0.125f); }
                if (b0) { float* a = &A[rb + rx0 * NCLS];
                    atomicAdd(a + l4.x, wy0 * 0.625f); atomicAdd(a + l4.y, wy0 * 0.875f);
                    atomicAdd(a + l4.z, wy0 * 0.875f); atomicAdd(a + l4.w, wy0 * 0.625f); }
                if (bp) { float* a = &A[rb + rxp * NCLS];
                    atomicAdd(a + l4.z, wy0 * 0.125f); atomicAdd(a + l4.w, wy0 * 0.375f); }
            }
            if (r1) {
                int rb = ((ry + 1) * TC) * NCLS;
                if (bm) { float* a = &A[rb + rxm * NCLS];
                    atomicAdd(a + l4.x, wy1 * 0.375f); atomicAdd(a + l4.y, wy1 * 0.125f); }
                if (b0) { float* a = &A[rb + rx0 * NCLS];
                    atomicAdd(a + l4.x, wy1 * 0.625f); atomicAdd(a + l4.y, wy1 * 0.875f);
                    atomicAdd(a + l4.z, wy1 * 0.875f); atomicAdd(a + l4.w, wy1 * 0.625f); }
                if (bp) { float* a = &A[rb + rxp * NCLS];
                    atomicAdd(a + l4.z, wy1 * 0.125f); atomicAdd(a + l4.w, wy1 * 0.375f); }
            }
            if (owned) {
                float u0 = wy0 * wy0, u1 = wy1 * wy1, u2t = 2.f * wy0 * wy1;
                int g00 = (y0 - Y0 + 1) * RW + rx0;      // ring idx of cell x=q-1
                float C0 = u0 * Gs_[g00]     + u1 * Gs_[g00 + RW]     + u2t * Gv_[g00];
                float C1 = u0 * Gs_[g00 + 1] + u1 * Gs_[g00 + RW + 1] + u2t * Gv_[g00 + 1];
                float C2 = u0 * Gs_[g00 + 2] + u1 * Gs_[g00 + RW + 2] + u2t * Gv_[g00 + 2];
                float D0 = 2.f * (u0 * Gh_[g00]     + u1 * Gh_[g00 + RW])     + u2t * Gda_[g00];
                float D1 = 2.f * (u0 * Gh_[g00 + 1] + u1 * Gh_[g00 + RW + 1]) + u2t * Gda_[g00 + 1];
                float d2a = fmaf(0.140625f, C0, fmaf(0.390625f, C1, 0.46875f * D0));
                float d2b = fmaf(0.015625f, C0, fmaf(0.765625f, C1, 0.21875f * D0));
                float d2c = fmaf(0.765625f, C1, fmaf(0.015625f, C2, 0.21875f * D1));
                float d2d = fmaf(0.390625f, C1, fmaf(0.140625f, C2, 0.46875f * D1));
                int wv = (tid >> 6) * NCLS;
                atomicAdd(&S2w[wv + l4.x], d2a); atomicAdd(&S2w[wv + l4.y], d2b);
                atomicAdd(&S2w[wv + l4.z], d2c); atomicAdd(&S2w[wv + l4.w], d2d);
            }
        } else {
            // image-border quads: per-pixel taps (clamp-shifted weights)
            int Ls[4] = {l4.x, l4.y, l4.z, l4.w};
            float u0 = wy0 * wy0, u1 = wy1 * wy1, u2t = 2.f * wy0 * wy1;
            int gyr = y0 - Y0 + 1;
            int wv = (tid >> 6) * NCLS;
#pragma unroll
            for (int j = 0; j < 4; j++) {
                int w = (q << 2) + j;
                int x0; float wx0, wx1;
                taps(w, LW - 1, x0, wx0, wx1);
                int rxa = x0 - X0, rxb = rxa + 1;
                int L = Ls[j];
                if (r0) {
                    int rb = (ry * TC) * NCLS;
                    if ((unsigned)rxa < (unsigned)TC) atomicAdd(&A[rb + rxa * NCLS + L], wy0 * wx0);
                    if ((unsigned)rxb < (unsigned)TC) atomicAdd(&A[rb + rxb * NCLS + L], wy0 * wx1);
                }
                if (r1) {
                    int rb = ((ry + 1) * TC) * NCLS;
                    if ((unsigned)rxa < (unsigned)TC) atomicAdd(&A[rb + rxa * NCLS + L], wy1 * wx0);
                    if ((unsigned)rxb < (unsigned)TC) atomicAdd(&A[rb + rxb * NCLS + L], wy1 * wx1);
                }
                if (owned) {
                    int gg = gyr * RW + (x0 - X0 + 1);
                    float Ca = u0 * Gs_[gg]     + u1 * Gs_[gg + RW]     + u2t * Gv_[gg];
                    float Cb = u0 * Gs_[gg + 1] + u1 * Gs_[gg + RW + 1] + u2t * Gv_[gg + 1];
                    float Dd = 2.f * (u0 * Gh_[gg] + u1 * Gh_[gg + RW]) + u2t * Gda_[gg];
                    float d2 = wx0 * wx0 * Ca + wx1 * wx1 * Cb + 2.f * wx0 * wx1 * Dd;
                    atomicAdd(&S2w[wv + L], d2);
                }
            }
        }
    };
    process(hA, qA, LA);
    if (vB) process(hB, qB, LB);
    __syncthreads();

    // ---- contract: thread (cc,cy) does row cy of channel cc; reduce over cy
    //      via shfl (cy = lane bits 0-2); cy==0 lane stores transposed ----
    {
        float ev[8] = {ev0.x, ev0.y, ev0.z, ev0.w, ev1.x, ev1.y, ev1.z, ev1.w};
        float acc[NCLS];
#pragma unroll
        for (int k = 0; k < NCLS; k++) acc[k] = 0.f;
#pragma unroll
        for (int cx = 0; cx < 8; cx++) {
            const float* Ar = &A[(cy * 8 + cx) * NCLS];
            float e = ev[cx];
#pragma unroll
            for (int k = 0; k < NCLS; k++) acc[k] = fmaf(Ar[k], e, acc[k]);
        }
#pragma unroll
        for (int k = 0; k < NCLS; k++) {
            acc[k] += __shfl_xor(acc[k], 1);
            acc[k] += __shfl_xor(acc[k], 2);
            acc[k] += __shfl_xor(acc[k], 4);
        }
        if (cy == 0) {
            float* pt = P_sumT + ((size_t)n * NSLOT + cc) * NTILE + tile;
#pragma unroll
            for (int k = 0; k < NCLS; k++) pt[(size_t)k * 32 * NTILE] = acc[k];
        }
    }
    if (tid < 8 * NCLS) {                     // cnt partials: 8 groups x 19 classes
        int g8 = tid / NCLS, k = tid - g8 * NCLS;
        float s = 0.f;
#pragma unroll
        for (int j = 0; j < 8; j++) s += A[(g8 * 8 + j) * NCLS + k];
        tmpc[k * 8 + g8] = s;
    }
    __syncthreads();
    if (tid < NCLS) {
        float s = 0.f;
#pragma unroll
        for (int g8 = 0; g8 < 8; g8++) s += tmpc[tid * 8 + g8];
        atomicAdd(&AccCS[n * 2 * NCLS + tid], s);
        float s2 = S2w[tid] + S2w[NCLS + tid] + S2w[2 * NCLS + tid] + S2w[3 * NCLS + tid];
        atomicAdd(&AccCS[n * 2 * NCLS + NCLS + tid], s2);
    }
}

// K2: per-image final: deterministic f64 reduce of P_sumT (contiguous runs),
// intra via S2 - 2 m.s + cnt |m|^2, inter pairwise, write out[n].
__global__ __launch_bounds__(256) void k_final(const float* __restrict__ P_sumT,
        const float* __restrict__ AccCS, float* __restrict__ out) {
    int n = blockIdx.x, tid = threadIdx.x;
    __shared__ double cs_d[NCLS * 33];
    __shared__ double m_d[NCLS * 33];
    __shared__ double cnt_d[NCLS], s2_d[NCLS];
    __shared__ double wpart[4];
    __shared__ double sIntra, sNfg;

    for (int idx = tid; idx < NSLOT; idx += 256) {
        const float4* p4 = (const float4*)(P_sumT + ((size_t)n * NSLOT + idx) * NTILE);
        double s = 0.0;
#pragma unroll 4
        for (int j = 0; j < NTILE / 4; j++) {
            float4 v = p4[j];
            s += (double)((v.x + v.y) + (v.z + v.w));
        }
        cs_d[(idx >> 5) * 33 + (idx & 31)] = s;   // idx = k*32+c
    }
    if (tid < NCLS) {
        cnt_d[tid] = (double)AccCS[n * 2 * NCLS + tid];
        s2_d[tid]  = (double)AccCS[n * 2 * NCLS + NCLS + tid];
    }
    __syncthreads();
    for (int idx = tid; idx < NSLOT; idx += 256) {
        int k = idx >> 5, c = idx & 31;
        m_d[k * 33 + c] = cs_d[k * 33 + c] / (cnt_d[k] + 1.0);
    }
    __syncthreads();
    double vi = 0.0, fg = 0.0;
    if (tid >= 1 && tid < NCLS && cnt_d[tid] > 0.0) {
        fg = 1.0;
        double dot = 0.0, mm = 0.0;
        for (int c = 0; c < CCH; c++) {
            double mv = m_d[tid * 33 + c];
            dot += mv * cs_d[tid * 33 + c];
            mm += mv * mv;
        }
        vi = (s2_d[tid] - 2.0 * dot + cnt_d[tid] * mm) * 0.03125 / (cnt_d[tid] + 1.0);
    }
    if (tid < 64) {
#pragma unroll
        for (int s_ = 32; s_ >= 1; s_ >>= 1) { vi += __shfl_xor(vi, s_); fg += __shfl_xor(fg, s_); }
        if (tid == 0) { sIntra = vi; sNfg = fg; }
    }
    double ve = 0.0;
    for (int t2 = tid; t2 < 324; t2 += 256) {
        int j = 1 + t2 / 18, k = 1 + t2 % 18;
        if (cnt_d[j] > 0.0 && cnt_d[k] > 0.0) {
            double s = 0.0;
            for (int c = 0; c < CCH; c++) {
                double d = m_d[j * 33 + c] - m_d[k * 33 + c];
                s += d * d;
            }
            ve += s * 0.03125;
        }
    }
#pragma unroll
    for (int s_ = 32; s_ >= 1; s_ >>= 1) ve += __shfl_xor(ve, s_);
    if ((tid & 63) == 0) wpart[tid >> 6] = ve;
    __syncthreads();
    if (tid == 0) {
        double inter = wpart[0] + wpart[1] + wpart[2] + wpart[3];
        out[n] = (float)(sIntra / sNfg - inter / (sNfg * sNfg));
    }
}

extern "C" void kernel_launch(void* const* d_in, const int* in_sizes, int n_in,
                              void* d_out, int out_size, void* d_ws, size_t ws_size,
                              hipStream_t stream) {
    const float* E = (const float*)d_in[0];   // (4,32,128,128) fp32
    const int* lab = (const int*)d_in[1];     // (4,512,512) int
    float* out = (float*)d_out;               // (4,) fp32

    float* P_sumT = (float*)d_ws;                            // 4*608*256 floats
    float* AccCS  = P_sumT + (size_t)NIMG * NSLOT * NTILE;   // 4*38 floats
    float* G      = AccCS + NIMG * 2 * NCLS;                 // 4*4*HWQ floats (1 MB)
    // AccCS zeroed by k_gram block (0,0); P_sumT/G fully overwritten

    k_gram <<<dim3(64, NIMG),    dim3(256), 0, stream>>>(E, G, AccCS);
    k_field<<<dim3(NTILE, NIMG), dim3(256), 0, stream>>>(E, lab, G, P_sumT, AccCS);
    k_final<<<dim3(NIMG),        dim3(256), 0, stream>>>(P_sumT, AccCS, out);
}

// Round 5
// 141.403 us; speedup vs baseline: 1.0123x; 1.0123x over previous
//
#include <hip/hip_runtime.h>

#define NIMG 4
#define NCLS 19
#define CCH  32
#define LH   128
#define LW   128
#define HH   512
#define WW   512
#define HWQ  (LH*LW)    // 16384 low-res pixels
#define HWP  (HH*WW)    // 262144 hi-res pixels

// k_field tiling: each block OWNS a disjoint TRxTC low-res region
#define TR 8
#define TC 8
#define NTX (LW/TC)       // 16
#define NTILE (256)       // tiles per image -> 1024 blocks total
#define TCELLS (TR*TC)    // 64
#define RW 10             // ring width  (X0-1 .. X0+8)
#define RING 100          // ring cells 10x10 (Y0-1 .. Y0+8)
#define NSLOT 608         // NCLS*CCH

// Bilinear taps for 128 -> 512, half-pixel convention. Edge taps shifted to a
// valid (b, b+1) pair with weights {1,0}/{0,1} (exact dyadic, same math).
__device__ __forceinline__ void taps(int v, int lim, int& i0, float& w0, float& w1) {
    int r = v & 3;
    int b = (v >> 2) + ((r < 2) ? -1 : 0);
    float f = 0.125f + 0.25f * (float)((r + 2) & 3);   // r: 0->.625 1->.875 2->.125 3->.375
    w0 = 1.f - f; w1 = f;
    if (b < 0)           { b = 0;       w0 = 1.f; w1 = 0.f; }
    else if (b >= lim)   { b = lim - 1; w0 = 0.f; w1 = 1.f; }
    i0 = b;
}

__device__ __forceinline__ float ring_fetch(const float* Gn, int i, int Y0, int X0) {
    int p = i / RING, r = i - p * RING;
    int gy = r / RW, gx = r - gy * RW;
    int yy = Y0 - 1 + gy; yy = yy < 0 ? 0 : (yy > LH - 1 ? LH - 1 : yy);
    int xx = X0 - 1 + gx; xx = xx < 0 ? 0 : (xx > LW - 1 ? LW - 1 : xx);
    return Gn[(size_t)p * HWQ + yy * LW + xx];
}

// K0: pre-summed Gram planes (over all 32 ch):
//   G[n][0]=<E,E>  G[n][1]=<E(y,x),E(y,x+1)>  G[n][2]=<E(y,x),E(y+1,x)>
//   G[n][3]=<E(y,x),E(y+1,x+1)> + <E(y,x+1),E(y+1,x)>
__global__ __launch_bounds__(256) void k_gram(const float* __restrict__ E,
        float* __restrict__ G) {
    int n = blockIdx.y, rp = blockIdx.x;
    int tid = threadIdx.x;
    int x = tid & 127, dy = tid >> 7;
    int y = rp * 2 + dy;
    int yn = (y < LH - 1) ? y + 1 : y;
    int xn = (x < LW - 1) ? x + 1 : x;
    bool fix = ((x & 63) == 63);             // wave edge: shfl_down(1) invalid
    const float* base = E + (size_t)n * CCH * HWQ;
    const float* Ea = base + y * LW + x;
    const float* Eb = base + yn * LW + x;
    const float* Eax = base + y * LW + xn;
    const float* Ebx = base + yn * LW + xn;
    float gs = 0.f, gh = 0.f, gv = 0.f, gda = 0.f;
#pragma unroll 8
    for (int c = 0; c < CCH; c++) {
        float a = Ea[(size_t)c * HWQ];
        float b = Eb[(size_t)c * HWQ];
        float ar = __shfl_down(a, 1);
        float br = __shfl_down(b, 1);
        if (fix) { ar = Eax[(size_t)c * HWQ]; br = Ebx[(size_t)c * HWQ]; }
        gs = fmaf(a, a, gs);
        gh = fmaf(a, ar, gh);
        gv = fmaf(a, b, gv);
        gda = fmaf(a, br, fmaf(ar, b, gda));
    }
    float* Gp = G + (size_t)n * 4 * HWQ + y * LW + x;
    Gp[0] = gs; Gp[HWQ] = gh; Gp[2 * HWQ] = gv; Gp[3 * HWQ] = gda;
}

// K1: ring-stage Gram, quad-row halo pass (A-field + per-pixel S2 via Gram),
// contract with in-wave reduce -> LDS stage -> one coalesced float4 store.
// cnt/S2: plain per-tile stores. Zero global atomics.
__global__ __launch_bounds__(256, 4) void k_field(const float* __restrict__ E,
        const int* __restrict__ lab, const float* __restrict__ G,
        float* __restrict__ P_sum, float* __restrict__ P_cnt, float* __restrict__ P_S2) {
    int tile = blockIdx.x, n = blockIdx.y;
    int ty = tile >> 4, tx = tile & 15;         // NTX=16
    int Y0 = ty * TR, X0 = tx * TC;
    __shared__ float A[TCELLS * NCLS];          // 4864 B [cell][k]
    __shared__ float Gt[4 * RING];              // 1600 B Gs,Gh,Gv,Gda ring
    __shared__ float S2w[4 * NCLS];             // per-wave S2 accumulators
    __shared__ float tmpc[NCLS * 8];            // cnt partials
    __shared__ __align__(16) float cs_l[NSLOT]; // contract result staging
    int tid = threadIdx.x;
    const int* ln = lab + (size_t)n * HWP;
    int h_lo = Y0 * 4 - 2;

    // ---- hoist all cold global loads: 2x lab int4, 2x E float4, 2x G ring ----
    int hA, qA, hB = 0, qB = 0; bool vB;
    int4 LA, LB = make_int4(0, 0, 0, 0);
    {
        int hr = tid / RW, qi = tid - hr * RW;
        hA = h_lo + hr; qA = X0 - 1 + qi;
        int hc = hA < 0 ? 0 : (hA > HH - 1 ? HH - 1 : hA);
        int qc = qA < 0 ? 0 : (qA > LW - 1 ? LW - 1 : qA);
        LA = *(const int4*)(ln + hc * WW + (qc << 2));
    }
    vB = (tid < 360 - 256);
    if (vB) {
        int i = tid + 256;
        int hr = i / RW, qi = i - hr * RW;
        hB = h_lo + hr; qB = X0 - 1 + qi;
        int hc = hB < 0 ? 0 : (hB > HH - 1 ? HH - 1 : hB);
        int qc = qB < 0 ? 0 : (qB > LW - 1 ? LW - 1 : qB);
        LB = *(const int4*)(ln + hc * WW + (qc << 2));
    }
    int cc = tid >> 3, cy = tid & 7;
    const float* Er = E + ((size_t)n * CCH + cc) * HWQ + (Y0 + cy) * LW + X0;
    float4 ev0 = *(const float4*)Er;
    float4 ev1 = *(const float4*)(Er + 4);
    const float* Gn = G + (size_t)n * 4 * HWQ;
    float rv0 = ring_fetch(Gn, tid, Y0, X0);
    bool rB = (tid < 4 * RING - 256);
    float rv1 = rB ? ring_fetch(Gn, tid + 256, Y0, X0) : 0.f;

    // ---- LDS init + ring write ----
    for (int i = tid; i < TCELLS * NCLS; i += 256) A[i] = 0.f;
    if (tid < 4 * NCLS) S2w[tid] = 0.f;
    Gt[tid] = rv0;
    if (rB) Gt[tid + 256] = rv1;
    __syncthreads();

    // ---- halo pass: one thread per 4-pixel quad-row (2 hoisted iterations) ----
    const float* Gs_ = Gt, *Gh_ = Gt + RING, *Gv_ = Gt + 2 * RING, *Gda_ = Gt + 3 * RING;
    auto process = [&](int h, int q, int4 l4) {
        if (h < 0 || h >= HH || q < 0 || q >= LW) return;
        int y0; float wy0, wy1;
        taps(h, LH - 1, y0, wy0, wy1);
        int ry = y0 - Y0;
        bool r0 = (unsigned)ry < (unsigned)TR, r1 = (unsigned)(ry + 1) < (unsigned)TR;
        int rxm = q - 1 - X0, rx0 = q - X0, rxp = q + 1 - X0;
        bool bm = (unsigned)rxm < (unsigned)TC, b0 = (unsigned)rx0 < (unsigned)TC,
             bp = (unsigned)rxp < (unsigned)TC;
        bool fast = (q >= 1) && (q <= 126);
        bool owned = ((unsigned)(h - Y0 * 4) < 32u) && b0;
        if (fast) {
            // x-weights: p0:(q-1:.375,q:.625) p1:(.125,.875) p2:(q:.875,q+1:.125) p3:(.625,.375)
            if (r0) {
                int rb = (ry * TC) * NCLS;
                if (bm) { float* a = &A[rb + rxm * NCLS];
                    atomicAdd(a + l4.x, wy0 * 0.375f); atomicAdd(a + l4.y, wy0 * 0.125f); }
                if (b0) { float* a = &A[rb + rx0 * NCLS];
                    atomicAdd(a + l4.x, wy0 * 0.625f); atomicAdd(a + l4.y, wy0 * 0.875f);
                    atomicAdd(a + l4.z, wy0 * 0.875f); atomicAdd(a + l4.w, wy0 * 0.625f); }
                if (bp) { float* a = &A[rb + rxp * NCLS];
                    atomicAdd(a + l4.z, wy0 * 0.125f); atomicAdd(a + l4.w, wy0 * 0.375f); }
            }
            if (r1) {
                int rb = ((ry + 1) * TC) * NCLS;
                if (bm) { float* a = &A[rb + rxm * NCLS];
                    atomicAdd(a + l4.x, wy1 * 0.375f); atomicAdd(a + l4.y, wy1 * 0.125f); }
                if (b0) { float* a = &A[rb + rx0 * NCLS];
                    atomicAdd(a + l4.x, wy1 * 0.625f); atomicAdd(a + l4.y, wy1 * 0.875f);
                    atomicAdd(a + l4.z, wy1 * 0.875f); atomicAdd(a + l4.w, wy1 * 0.625f); }
                if (bp) { float* a = &A[rb + rxp * NCLS];
                    atomicAdd(a + l4.z, wy1 * 0.125f); atomicAdd(a + l4.w, wy1 * 0.375f); }
            }
            if (owned) {
                float u0 = wy0 * wy0, u1 = wy1 * wy1, u2t = 2.f * wy0 * wy1;
                int g00 = (y0 - Y0 + 1) * RW + rx0;      // ring idx of cell x=q-1
                float C0 = u0 * Gs_[g00]     + u1 * Gs_[g00 + RW]     + u2t * Gv_[g00];
                float C1 = u0 * Gs_[g00 + 1] + u1 * Gs_[g00 + RW + 1] + u2t * Gv_[g00 + 1];
                float C2 = u0 * Gs_[g00 + 2] + u1 * Gs_[g00 + RW + 2] + u2t * Gv_[g00 + 2];
                float D0 = 2.f * (u0 * Gh_[g00]     + u1 * Gh_[g00 + RW])     + u2t * Gda_[g00];
                float D1 = 2.f * (u0 * Gh_[g00 + 1] + u1 * Gh_[g00 + RW + 1]) + u2t * Gda_[g00 + 1];
                float d2a = fmaf(0.140625f, C0, fmaf(0.390625f, C1, 0.46875f * D0));
                float d2b = fmaf(0.015625f, C0, fmaf(0.765625f, C1, 0.21875f * D0));
                float d2c = fmaf(0.765625f, C1, fmaf(0.015625f, C2, 0.21875f * D1));
                float d2d = fmaf(0.390625f, C1, fmaf(0.140625f, C2, 0.46875f * D1));
                int wv = (tid >> 6) * NCLS;
                atomicAdd(&S2w[wv + l4.x], d2a); atomicAdd(&S2w[wv + l4.y], d2b);
                atomicAdd(&S2w[wv + l4.z], d2c); atomicAdd(&S2w[wv + l4.w], d2d);
            }
        } else {
            // image-border quads: per-pixel taps (clamp-shifted weights)
            int Ls[4] = {l4.x, l4.y, l4.z, l4.w};
            float u0 = wy0 * wy0, u1 = wy1 * wy1, u2t = 2.f * wy0 * wy1;
            int gyr = y0 - Y0 + 1;
            int wv = (tid >> 6) * NCLS;
#pragma unroll
            for (int j = 0; j < 4; j++) {
                int w = (q << 2) + j;
                int x0; float wx0, wx1;
                taps(w, LW - 1, x0, wx0, wx1);
                int rxa = x0 - X0, rxb = rxa + 1;
                int L = Ls[j];
                if (r0) {
                    int rb = (ry * TC) * NCLS;
                    if ((unsigned)rxa < (unsigned)TC) atomicAdd(&A[rb + rxa * NCLS + L], wy0 * wx0);
                    if ((unsigned)rxb < (unsigned)TC) atomicAdd(&A[rb + rxb * NCLS + L], wy0 * wx1);
                }
                if (r1) {
                    int rb = ((ry + 1) * TC) * NCLS;
                    if ((unsigned)rxa < (unsigned)TC) atomicAdd(&A[rb + rxa * NCLS + L], wy1 * wx0);
                    if ((unsigned)rxb < (unsigned)TC) atomicAdd(&A[rb + rxb * NCLS + L], wy1 * wx1);
                }
                if (owned) {
                    int gg = gyr * RW + (x0 - X0 + 1);
                    float Ca = u0 * Gs_[gg]     + u1 * Gs_[gg + RW]     + u2t * Gv_[gg];
                    float Cb = u0 * Gs_[gg + 1] + u1 * Gs_[gg + RW + 1] + u2t * Gv_[gg + 1];
                    float Dd = 2.f * (u0 * Gh_[gg] + u1 * Gh_[gg + RW]) + u2t * Gda_[gg];
                    float d2 = wx0 * wx0 * Ca + wx1 * wx1 * Cb + 2.f * wx0 * wx1 * Dd;
                    atomicAdd(&S2w[wv + L], d2);
                }
            }
        }
    };
    process(hA, qA, LA);
    if (vB) process(hB, qB, LB);
    __syncthreads();

    // ---- contract: thread (cc,cy) does row cy of channel cc; reduce over cy
    //      via shfl (cy = lane bits 0-2); cy==0 lane stages into LDS ----
    {
        float ev[8] = {ev0.x, ev0.y, ev0.z, ev0.w, ev1.x, ev1.y, ev1.z, ev1.w};
        float acc[NCLS];
#pragma unroll
        for (int k = 0; k < NCLS; k++) acc[k] = 0.f;
#pragma unroll
        for (int cx = 0; cx < 8; cx++) {
            const float* Ar = &A[(cy * 8 + cx) * NCLS];
            float e = ev[cx];
#pragma unroll
            for (int k = 0; k < NCLS; k++) acc[k] = fmaf(Ar[k], e, acc[k]);
        }
#pragma unroll
        for (int k = 0; k < NCLS; k++) {
            acc[k] += __shfl_xor(acc[k], 1);
            acc[k] += __shfl_xor(acc[k], 2);
            acc[k] += __shfl_xor(acc[k], 4);
        }
        if (cy == 0) {
#pragma unroll
            for (int k = 0; k < NCLS; k++) cs_l[k * CCH + cc] = acc[k];
        }
    }
    if (tid < 8 * NCLS) {                     // cnt partials: 8 groups x 19 classes
        int g8 = tid / NCLS, k = tid - g8 * NCLS;
        float s = 0.f;
#pragma unroll
        for (int j = 0; j < 8; j++) s += A[(g8 * 8 + j) * NCLS + k];
        tmpc[k * 8 + g8] = s;
    }
    __syncthreads();

    // ---- coalesced outputs: 152 float4 P_sum + 19 cnt + 19 S2 ----
    float* Ps = P_sum + (size_t)(n * NTILE + tile) * NSLOT;
    if (tid < NSLOT / 4) ((float4*)Ps)[tid] = ((const float4*)cs_l)[tid];
    if (tid < NCLS) {
        float s = 0.f;
#pragma unroll
        for (int g8 = 0; g8 < 8; g8++) s += tmpc[tid * 8 + g8];
        P_cnt[(size_t)(n * NTILE + tile) * NCLS + tid] = s;
        P_S2[(size_t)(n * NTILE + tile) * NCLS + tid] =
            S2w[tid] + S2w[NCLS + tid] + S2w[2 * NCLS + tid] + S2w[3 * NCLS + tid];
    }
}

// K2: per-image final: deterministic f64 reduce of P_sum/P_cnt/P_S2,
// intra via S2 - 2 m.s + cnt |m|^2, inter pairwise, write out[n].
__global__ __launch_bounds__(256) void k_final(const float* __restrict__ P_sum,
        const float* __restrict__ P_cnt, const float* __restrict__ P_S2,
        float* __restrict__ out) {
    int n = blockIdx.x, tid = threadIdx.x;
    __shared__ double cs_d[NCLS * 33];
    __shared__ double m_d[NCLS * 33];
    __shared__ double cnt_d[NCLS], s2_d[NCLS];
    __shared__ double rk1[NCLS * 9], rk2[NCLS * 9];
    __shared__ double wpart[4];
    __shared__ double sIntra, sNfg;

    // P_sum: slot i4 (152 float4), reduce over 256 tiles (stride 152 float4)
    for (int i4 = tid; i4 < NSLOT / 4; i4 += 256) {
        const float4* p4 = (const float4*)(P_sum + (size_t)n * NTILE * NSLOT) + i4;
        double sx = 0.0, sy = 0.0, sz = 0.0, sw = 0.0;
#pragma unroll 4
        for (int t = 0; t < NTILE; t++) {
            float4 v = p4[(size_t)t * (NSLOT / 4)];
            sx += v.x; sy += v.y; sz += v.z; sw += v.w;
        }
        int idx = i4 * 4;                      // = k*32 + c
        int k = idx >> 5, c = idx & 31;
        cs_d[k * 33 + c] = sx; cs_d[k * 33 + c + 1] = sy;
        cs_d[k * 33 + c + 2] = sz; cs_d[k * 33 + c + 3] = sw;
    }
    if (tid < 8 * NCLS) {                      // cnt/S2: 19 classes x 8 groups of 32
        int k = tid >> 3, g = tid & 7;
        const float* p1 = P_cnt + ((size_t)n * NTILE + g * 32) * NCLS + k;
        const float* p2 = P_S2  + ((size_t)n * NTILE + g * 32) * NCLS + k;
        double s1 = 0.0, s2 = 0.0;
#pragma unroll 4
        for (int j = 0; j < 32; j++) { s1 += p1[j * NCLS]; s2 += p2[j * NCLS]; }
        rk1[k * 9 + g] = s1; rk2[k * 9 + g] = s2;
    }
    __syncthreads();
    if (tid < NCLS) {
        double s1 = 0.0, s2 = 0.0;
#pragma unroll
        for (int g = 0; g < 8; g++) { s1 += rk1[tid * 9 + g]; s2 += rk2[tid * 9 + g]; }
        cnt_d[tid] = s1; s2_d[tid] = s2;
    }
    __syncthreads();
    for (int idx = tid; idx < NSLOT; idx += 256) {
        int k = idx >> 5, c = idx & 31;
        m_d[k * 33 + c] = cs_d[k * 33 + c] / (cnt_d[k] + 1.0);
    }
    __syncthreads();
    double vi = 0.0, fg = 0.0;
    if (tid >= 1 && tid < NCLS && cnt_d[tid] > 0.0) {
        fg = 1.0;
        double dot = 0.0, mm = 0.0;
        for (int c = 0; c < CCH; c++) {
            double mv = m_d[tid * 33 + c];
            dot += mv * cs_d[tid * 33 + c];
            mm += mv * mv;
        }
        vi = (s2_d[tid] - 2.0 * dot + cnt_d[tid] * mm) * 0.03125 / (cnt_d[tid] + 1.0);
    }
    if (tid < 64) {
#pragma unroll
        for (int s_ = 32; s_ >= 1; s_ >>= 1) { vi += __shfl_xor(vi, s_); fg += __shfl_xor(fg, s_); }
        if (tid == 0) { sIntra = vi; sNfg = fg; }
    }
    double ve = 0.0;
    for (int t2 = tid; t2 < 324; t2 += 256) {
        int j = 1 + t2 / 18, k = 1 + t2 % 18;
        if (cnt_d[j] > 0.0 && cnt_d[k] > 0.0) {
            double s = 0.0;
            for (int c = 0; c < CCH; c++) {
                double d = m_d[j * 33 + c] - m_d[k * 33 + c];
                s += d * d;
            }
            ve += s * 0.03125;
        }
    }
#pragma unroll
    for (int s_ = 32; s_ >= 1; s_ >>= 1) ve += __shfl_xor(ve, s_);
    if ((tid & 63) == 0) wpart[tid >> 6] = ve;
    __syncthreads();
    if (tid == 0) {
        double inter = wpart[0] + wpart[1] + wpart[2] + wpart[3];
        out[n] = (float)(sIntra / sNfg - inter / (sNfg * sNfg));
    }
}

extern "C" void kernel_launch(void* const* d_in, const int* in_sizes, int n_in,
                              void* d_out, int out_size, void* d_ws, size_t ws_size,
                              hipStream_t stream) {
    const float* E = (const float*)d_in[0];   // (4,32,128,128) fp32
    const int* lab = (const int*)d_in[1];     // (4,512,512) int
    float* out = (float*)d_out;               // (4,) fp32

    float* P_sum = (float*)d_ws;                             // 4*256*608 floats
    float* P_cnt = P_sum + (size_t)NIMG * NTILE * NSLOT;     // 4*256*19
    float* P_S2  = P_cnt + (size_t)NIMG * NTILE * NCLS;      // 4*256*19
    float* G     = P_S2  + (size_t)NIMG * NTILE * NCLS;      // 4*4*HWQ (1 MB)
    // all workspace slots fully overwritten every call -> no zeroing, no atomics

    k_gram <<<dim3(64, NIMG),    dim3(256), 0, stream>>>(E, G);
    k_field<<<dim3(NTILE, NIMG), dim3(256), 0, stream>>>(E, lab, G, P_sum, P_cnt, P_S2);
    k_final<<<dim3(NIMG),        dim3(256), 0, stream>>>(P_sum, P_cnt, P_S2, out);
}

// Round 6
// 135.484 us; speedup vs baseline: 1.0566x; 1.0437x over previous
//
#include <hip/hip_runtime.h>

#define NIMG 4
#define NCLS 19
#define CCH  32
#define LH   128
#define LW   128
#define HH   512
#define WW   512
#define HWQ  (LH*LW)    // 16384 low-res pixels
#define HWP  (HH*WW)    // 262144 hi-res pixels

// k_field tiling: each block OWNS a disjoint TRxTC low-res region
#define TR 4
#define TC 8
#define NTX 16            // LW/TC
#define NTY 32            // LH/TR
#define NTILE 512         // tiles per image -> 2048 blocks total
#define TCELLS 32         // TR*TC
#define RW 10             // ring width  (X0-1 .. X0+8)
#define RROWS 6           // ring rows   (Y0-1 .. Y0+4)
#define RING 60           // RROWS*RW
#define NSLOT 608         // NCLS*CCH
#define HITEMS 200        // halo quad-row items: (TR*4+4)*RW

// Bilinear taps for 128 -> 512, half-pixel convention. Edge taps shifted to a
// valid (b, b+1) pair with weights {1,0}/{0,1} (exact dyadic, same math).
__device__ __forceinline__ void taps(int v, int lim, int& i0, float& w0, float& w1) {
    int r = v & 3;
    int b = (v >> 2) + ((r < 2) ? -1 : 0);
    float f = 0.125f + 0.25f * (float)((r + 2) & 3);   // r: 0->.625 1->.875 2->.125 3->.375
    w0 = 1.f - f; w1 = f;
    if (b < 0)           { b = 0;       w0 = 1.f; w1 = 0.f; }
    else if (b >= lim)   { b = lim - 1; w0 = 0.f; w1 = 1.f; }
    i0 = b;
}

__device__ __forceinline__ float ring_fetch(const float* Gn, int i, int Y0, int X0) {
    int p = i / RING, r = i - p * RING;
    int gy = r / RW, gx = r - gy * RW;
    int yy = Y0 - 1 + gy; yy = yy < 0 ? 0 : (yy > LH - 1 ? LH - 1 : yy);
    int xx = X0 - 1 + gx; xx = xx < 0 ? 0 : (xx > LW - 1 ? LW - 1 : xx);
    return Gn[(size_t)p * HWQ + yy * LW + xx];
}

// K0: pre-summed Gram planes (over all 32 ch):
//   G[n][0]=<E,E>  G[n][1]=<E(y,x),E(y,x+1)>  G[n][2]=<E(y,x),E(y+1,x)>
//   G[n][3]=<E(y,x),E(y+1,x+1)> + <E(y,x+1),E(y+1,x)>
__global__ __launch_bounds__(256) void k_gram(const float* __restrict__ E,
        float* __restrict__ G) {
    int n = blockIdx.y, rp = blockIdx.x;
    int tid = threadIdx.x;
    int x = tid & 127, dy = tid >> 7;
    int y = rp * 2 + dy;
    int yn = (y < LH - 1) ? y + 1 : y;
    int xn = (x < LW - 1) ? x + 1 : x;
    bool fix = ((x & 63) == 63);             // wave edge: shfl_down(1) invalid
    const float* base = E + (size_t)n * CCH * HWQ;
    const float* Ea = base + y * LW + x;
    const float* Eb = base + yn * LW + x;
    const float* Eax = base + y * LW + xn;
    const float* Ebx = base + yn * LW + xn;
    float gs = 0.f, gh = 0.f, gv = 0.f, gda = 0.f;
#pragma unroll 8
    for (int c = 0; c < CCH; c++) {
        float a = Ea[(size_t)c * HWQ];
        float b = Eb[(size_t)c * HWQ];
        float ar = __shfl_down(a, 1);
        float br = __shfl_down(b, 1);
        if (fix) { ar = Eax[(size_t)c * HWQ]; br = Ebx[(size_t)c * HWQ]; }
        gs = fmaf(a, a, gs);
        gh = fmaf(a, ar, gh);
        gv = fmaf(a, b, gv);
        gda = fmaf(a, br, fmaf(ar, b, gda));
    }
    float* Gp = G + (size_t)n * 4 * HWQ + y * LW + x;
    Gp[0] = gs; Gp[HWQ] = gh; Gp[2 * HWQ] = gv; Gp[3 * HWQ] = gda;
}

// K1: ring-stage Gram, single-shot halo pass (A-field + per-pixel S2 via Gram),
// contract with in-wave reduce -> LDS stage -> coalesced float4 store.
// A layout [k][cell] -> conflict-free LDS atomic banks. Zero global atomics.
__global__ __launch_bounds__(256, 8) void k_field(const float* __restrict__ E,
        const int* __restrict__ lab, const float* __restrict__ G,
        float* __restrict__ P_sum, float* __restrict__ P_cnt, float* __restrict__ P_S2) {
    int tile = blockIdx.x, n = blockIdx.y;
    int ty = tile >> 4, tx = tile & 15;         // NTX=16
    int Y0 = ty * TR, X0 = tx * TC;
    __shared__ float A[NCLS * TCELLS];          // 2432 B  [k][cell]
    __shared__ float Gt[4 * RING];              // 960 B   Gs,Gh,Gv,Gda ring
    __shared__ float S2w[16 * NCLS];            // 1216 B  16-copy S2 accumulators
    __shared__ float tmpc[NCLS * 8];            // cnt partials
    __shared__ __align__(16) float cs_l[NSLOT]; // contract result staging
    int tid = threadIdx.x;

    // ---- hoist all cold global loads (one each): lab int4, E float4, G ring ----
    const int* ln = lab + (size_t)n * HWP;
    int h_lo = Y0 * 4 - 2;
    int hr = tid / RW, qi = tid - hr * RW;
    int h = h_lo + hr, q = X0 - 1 + qi;
    int hc = h < 0 ? 0 : (h > HH - 1 ? HH - 1 : h);
    int qc = q < 0 ? 0 : (q > LW - 1 ? LW - 1 : q);
    int4 L4 = *(const int4*)(ln + hc * WW + (qc << 2));

    int cc = tid >> 3, sub = tid & 7, cy = sub >> 1, hh = sub & 1;
    const float* Er = E + ((size_t)n * CCH + cc) * HWQ + (Y0 + cy) * LW + X0 + hh * 4;
    float4 ev = *(const float4*)Er;

    const float* Gn = G + (size_t)n * 4 * HWQ;
    float rv = (tid < 4 * RING) ? ring_fetch(Gn, tid, Y0, X0) : 0.f;

    // ---- LDS init + ring write ----
    for (int i = tid; i < NCLS * TCELLS; i += 256) A[i] = 0.f;
    for (int i = tid; i < 16 * NCLS; i += 256) S2w[i] = 0.f;
    if (tid < 4 * RING) Gt[tid] = rv;
    __syncthreads();

    // ---- halo pass: one thread per 4-pixel quad-row, single shot ----
    const float* Gs_ = Gt, *Gh_ = Gt + RING, *Gv_ = Gt + 2 * RING, *Gda_ = Gt + 3 * RING;
    if (tid < HITEMS && h >= 0 && h < HH && q >= 0 && q < LW) {
        int y0; float wy0, wy1;
        taps(h, LH - 1, y0, wy0, wy1);
        int ry = y0 - Y0;
        bool r0 = (unsigned)ry < (unsigned)TR, r1 = (unsigned)(ry + 1) < (unsigned)TR;
        int rxm = q - 1 - X0, rx0 = q - X0, rxp = q + 1 - X0;
        bool bm = (unsigned)rxm < (unsigned)TC, b0 = (unsigned)rx0 < (unsigned)TC,
             bp = (unsigned)rxp < (unsigned)TC;
        bool fast = (q >= 1) && (q <= 126);
        bool owned = ((unsigned)(h - Y0 * 4) < (unsigned)(TR * 4)) && b0;
        int wv = (tid >> 4) * NCLS;
        if (fast) {
            // x-weights: p0:(q-1:.375,q:.625) p1:(.125,.875) p2:(q:.875,q+1:.125) p3:(.625,.375)
            if (r0) {
                int rb = ry * TC;
                if (bm) { float* a = &A[rb + rxm];
                    atomicAdd(a + L4.x * TCELLS, wy0 * 0.375f); atomicAdd(a + L4.y * TCELLS, wy0 * 0.125f); }
                if (b0) { float* a = &A[rb + rx0];
                    atomicAdd(a + L4.x * TCELLS, wy0 * 0.625f); atomicAdd(a + L4.y * TCELLS, wy0 * 0.875f);
                    atomicAdd(a + L4.z * TCELLS, wy0 * 0.875f); atomicAdd(a + L4.w * TCELLS, wy0 * 0.625f); }
                if (bp) { float* a = &A[rb + rxp];
                    atomicAdd(a + L4.z * TCELLS, wy0 * 0.125f); atomicAdd(a + L4.w * TCELLS, wy0 * 0.375f); }
            }
            if (r1) {
                int rb = (ry + 1) * TC;
                if (bm) { float* a = &A[rb + rxm];
                    atomicAdd(a + L4.x * TCELLS, wy1 * 0.375f); atomicAdd(a + L4.y * TCELLS, wy1 * 0.125f); }
                if (b0) { float* a = &A[rb + rx0];
                    atomicAdd(a + L4.x * TCELLS, wy1 * 0.625f); atomicAdd(a + L4.y * TCELLS, wy1 * 0.875f);
                    atomicAdd(a + L4.z * TCELLS, wy1 * 0.875f); atomicAdd(a + L4.w * TCELLS, wy1 * 0.625f); }
                if (bp) { float* a = &A[rb + rxp];
                    atomicAdd(a + L4.z * TCELLS, wy1 * 0.125f); atomicAdd(a + L4.w * TCELLS, wy1 * 0.375f); }
            }
            if (owned) {
                // d2 = s0*C(x0) + s1*C(x0+1) + s2*D(x0), D = 2<col(x),col(x+1)>
                float u0 = wy0 * wy0, u1 = wy1 * wy1, u2t = 2.f * wy0 * wy1;
                int g00 = (y0 - Y0 + 1) * RW + rx0;      // ring idx of cell x=q-1
                float C0 = u0 * Gs_[g00]     + u1 * Gs_[g00 + RW]     + u2t * Gv_[g00];
                float C1 = u0 * Gs_[g00 + 1] + u1 * Gs_[g00 + RW + 1] + u2t * Gv_[g00 + 1];
                float C2 = u0 * Gs_[g00 + 2] + u1 * Gs_[g00 + RW + 2] + u2t * Gv_[g00 + 2];
                float D0 = 2.f * (u0 * Gh_[g00]     + u1 * Gh_[g00 + RW])     + u2t * Gda_[g00];
                float D1 = 2.f * (u0 * Gh_[g00 + 1] + u1 * Gh_[g00 + RW + 1]) + u2t * Gda_[g00 + 1];
                float d2a = fmaf(0.140625f, C0, fmaf(0.390625f, C1, 0.234375f * D0));
                float d2b = fmaf(0.015625f, C0, fmaf(0.765625f, C1, 0.109375f * D0));
                float d2c = fmaf(0.765625f, C1, fmaf(0.015625f, C2, 0.109375f * D1));
                float d2d = fmaf(0.390625f, C1, fmaf(0.140625f, C2, 0.234375f * D1));
                atomicAdd(&S2w[wv + L4.x], d2a); atomicAdd(&S2w[wv + L4.y], d2b);
                atomicAdd(&S2w[wv + L4.z], d2c); atomicAdd(&S2w[wv + L4.w], d2d);
            }
        } else {
            // image-border quads: per-pixel taps (clamp-shifted weights)
            int Ls[4] = {L4.x, L4.y, L4.z, L4.w};
            float u0 = wy0 * wy0, u1 = wy1 * wy1, u2t = 2.f * wy0 * wy1;
            int gyr = y0 - Y0 + 1;
#pragma unroll
            for (int j = 0; j < 4; j++) {
                int w = (q << 2) + j;
                int x0; float wx0, wx1;
                taps(w, LW - 1, x0, wx0, wx1);
                int rxa = x0 - X0, rxb = rxa + 1;
                int L = Ls[j];
                if (r0) {
                    int rb = ry * TC;
                    if ((unsigned)rxa < (unsigned)TC) atomicAdd(&A[L * TCELLS + rb + rxa], wy0 * wx0);
                    if ((unsigned)rxb < (unsigned)TC) atomicAdd(&A[L * TCELLS + rb + rxb], wy0 * wx1);
                }
                if (r1) {
                    int rb = (ry + 1) * TC;
                    if ((unsigned)rxa < (unsigned)TC) atomicAdd(&A[L * TCELLS + rb + rxa], wy1 * wx0);
                    if ((unsigned)rxb < (unsigned)TC) atomicAdd(&A[L * TCELLS + rb + rxb], wy1 * wx1);
                }
                if (owned) {
                    int gg = gyr * RW + (x0 - X0 + 1);
                    float Ca = u0 * Gs_[gg]     + u1 * Gs_[gg + RW]     + u2t * Gv_[gg];
                    float Cb = u0 * Gs_[gg + 1] + u1 * Gs_[gg + RW + 1] + u2t * Gv_[gg + 1];
                    float Dd = 2.f * (u0 * Gh_[gg] + u1 * Gh_[gg + RW]) + u2t * Gda_[gg];
                    float d2 = wx0 * wx0 * Ca + wx1 * wx1 * Cb + wx0 * wx1 * Dd;
                    atomicAdd(&S2w[wv + L], d2);
                }
            }
        }
    }
    __syncthreads();

    // ---- contract: thread (cc, cy, hh) does 4 cells; reduce over lane bits 0-2
    //      via shfl; sub==0 lane stages into LDS. A reads broadcast per wave. ----
    {
        float ev_[4] = {ev.x, ev.y, ev.z, ev.w};
        float acc[NCLS];
#pragma unroll
        for (int k = 0; k < NCLS; k++) acc[k] = 0.f;
        int base = cy * TC + hh * 4;
#pragma unroll
        for (int cx = 0; cx < 4; cx++) {
            float e = ev_[cx];
            const float* Ac = &A[base + cx];
#pragma unroll
            for (int k = 0; k < NCLS; k++) acc[k] = fmaf(Ac[k * TCELLS], e, acc[k]);
        }
#pragma unroll
        for (int k = 0; k < NCLS; k++) {
            acc[k] += __shfl_xor(acc[k], 1);
            acc[k] += __shfl_xor(acc[k], 2);
            acc[k] += __shfl_xor(acc[k], 4);
        }
        if (sub == 0) {
#pragma unroll
            for (int k = 0; k < NCLS; k++) cs_l[k * CCH + cc] = acc[k];
        }
    }
    if (tid < 8 * NCLS) {                     // cnt partials: 8 groups x 19 classes
        int g8 = tid / NCLS, k = tid - g8 * NCLS;
        float s = 0.f;
#pragma unroll
        for (int j = 0; j < 4; j++) s += A[k * TCELLS + g8 * 4 + j];
        tmpc[k * 8 + g8] = s;
    }
    __syncthreads();

    // ---- coalesced outputs: 152 float4 P_sum + 19 cnt + 19 S2 ----
    float* Ps = P_sum + (size_t)(n * NTILE + tile) * NSLOT;
    if (tid < NSLOT / 4) ((float4*)Ps)[tid] = ((const float4*)cs_l)[tid];
    if (tid < NCLS) {
        float s = 0.f;
#pragma unroll
        for (int g8 = 0; g8 < 8; g8++) s += tmpc[tid * 8 + g8];
        P_cnt[(size_t)(n * NTILE + tile) * NCLS + tid] = s;
        float s2 = 0.f;
#pragma unroll
        for (int j = 0; j < 16; j++) s2 += S2w[j * NCLS + tid];
        P_S2[(size_t)(n * NTILE + tile) * NCLS + tid] = s2;
    }
}

// K2: per-image final (1024 threads): 16 waves reduce 32 tiles each (f64, LDS),
// cross-wave reduce, then intra/inter math; deterministic order. Write out[n].
__global__ __launch_bounds__(1024) void k_final(const float* __restrict__ P_sum,
        const float* __restrict__ P_cnt, const float* __restrict__ P_S2,
        float* __restrict__ out) {
    int n = blockIdx.x, tid = threadIdx.x;
    __shared__ double wred[16 * NSLOT];        // 77.8 KB
    __shared__ double cs_d[NCLS * 33];
    __shared__ double m_d[NCLS * 33];
    __shared__ double cnt_d[NCLS], s2_d[NCLS];
    __shared__ double rkb1[64 * 20], rkb2[64 * 20];
    __shared__ double wpart[16];
    __shared__ double sIntra, sNfg;
    int wv = tid >> 6, lane = tid & 63;

    // stage A: P_sum, wave wv reduces tiles wv, wv+16, ... (coalesced float4)
    {
        double a0x = 0, a0y = 0, a0z = 0, a0w = 0;
        double a1x = 0, a1y = 0, a1z = 0, a1w = 0;
        double a2x = 0, a2y = 0, a2z = 0, a2w = 0;
        const float4* Pb = (const float4*)(P_sum + (size_t)n * NTILE * NSLOT);
#pragma unroll 2
        for (int t = wv; t < NTILE; t += 16) {
            const float4* pt = Pb + (size_t)t * (NSLOT / 4);
            float4 v0 = pt[lane];
            float4 v1 = pt[lane + 64];
            a0x += v0.x; a0y += v0.y; a0z += v0.z; a0w += v0.w;
            a1x += v1.x; a1y += v1.y; a1z += v1.z; a1w += v1.w;
            if (lane < 24) {
                float4 v2 = pt[lane + 128];
                a2x += v2.x; a2y += v2.y; a2z += v2.z; a2w += v2.w;
            }
        }
        double* wr = wred + wv * NSLOT;
        wr[lane * 4 + 0] = a0x; wr[lane * 4 + 1] = a0y;
        wr[lane * 4 + 2] = a0z; wr[lane * 4 + 3] = a0w;
        wr[(lane + 64) * 4 + 0] = a1x; wr[(lane + 64) * 4 + 1] = a1y;
        wr[(lane + 64) * 4 + 2] = a1z; wr[(lane + 64) * 4 + 3] = a1w;
        if (lane < 24) {
            wr[(lane + 128) * 4 + 0] = a2x; wr[(lane + 128) * 4 + 1] = a2y;
            wr[(lane + 128) * 4 + 2] = a2z; wr[(lane + 128) * 4 + 3] = a2w;
        }
    }
    // cnt/S2 partials: 64 groups x 19 classes, 8 tiles each
    for (int idx = tid; idx < 64 * NCLS; idx += 1024) {
        int g = idx / NCLS, k = idx - g * NCLS;
        const float* p1 = P_cnt + ((size_t)n * NTILE + g * 8) * NCLS + k;
        const float* p2 = P_S2  + ((size_t)n * NTILE + g * 8) * NCLS + k;
        double s1 = 0.0, s2 = 0.0;
#pragma unroll
        for (int j = 0; j < 8; j++) { s1 += p1[j * NCLS]; s2 += p2[j * NCLS]; }
        rkb1[g * 20 + k] = s1; rkb2[g * 20 + k] = s2;
    }
    __syncthreads();
    for (int s = tid; s < NSLOT; s += 1024) {
        double acc = 0.0;
#pragma unroll
        for (int w = 0; w < 16; w++) acc += wred[w * NSLOT + s];
        cs_d[(s >> 5) * 33 + (s & 31)] = acc;    // s = k*32 + c
    }
    if (tid < NCLS) {
        double s1 = 0.0, s2 = 0.0;
        for (int g = 0; g < 64; g++) { s1 += rkb1[g * 20 + tid]; s2 += rkb2[g * 20 + tid]; }
        cnt_d[tid] = s1; s2_d[tid] = s2;
    }
    __syncthreads();
    for (int idx = tid; idx < NSLOT; idx += 1024) {
        int k = idx >> 5, c = idx & 31;
        m_d[k * 33 + c] = cs_d[k * 33 + c] / (cnt_d[k] + 1.0);
    }
    __syncthreads();
    // intra + n_fg (t<19 sits in wave 0)
    double vi = 0.0, fg = 0.0;
    if (tid >= 1 && tid < NCLS && cnt_d[tid] > 0.0) {
        fg = 1.0;
        double dot = 0.0, mm = 0.0;
        for (int c = 0; c < CCH; c++) {
            double mv = m_d[tid * 33 + c];
            dot += mv * cs_d[tid * 33 + c];
            mm += mv * mv;
        }
        vi = (s2_d[tid] - 2.0 * dot + cnt_d[tid] * mm) * 0.03125 / (cnt_d[tid] + 1.0);
    }
    if (tid < 64) {
#pragma unroll
        for (int s_ = 32; s_ >= 1; s_ >>= 1) { vi += __shfl_xor(vi, s_); fg += __shfl_xor(fg, s_); }
        if (tid == 0) { sIntra = vi; sNfg = fg; }
    }
    // inter: 18x18 foreground pairs (single shot, 1024 threads)
    double ve = 0.0;
    if (tid < 324) {
        int j = 1 + tid / 18, k = 1 + tid % 18;
        if (cnt_d[j] > 0.0 && cnt_d[k] > 0.0) {
            double s = 0.0;
            for (int c = 0; c < CCH; c++) {
                double d = m_d[j * 33 + c] - m_d[k * 33 + c];
                s += d * d;
            }
            ve = s * 0.03125;
        }
    }
#pragma unroll
    for (int s_ = 32; s_ >= 1; s_ >>= 1) ve += __shfl_xor(ve, s_);
    if (lane == 0) wpart[wv] = ve;
    __syncthreads();
    if (tid == 0) {
        double inter = 0.0;
#pragma unroll
        for (int w = 0; w < 16; w++) inter += wpart[w];
        out[n] = (float)(sIntra / sNfg - inter / (sNfg * sNfg));
    }
}

extern "C" void kernel_launch(void* const* d_in, const int* in_sizes, int n_in,
                              void* d_out, int out_size, void* d_ws, size_t ws_size,
                              hipStream_t stream) {
    const float* E = (const float*)d_in[0];   // (4,32,128,128) fp32
    const int* lab = (const int*)d_in[1];     // (4,512,512) int
    float* out = (float*)d_out;               // (4,) fp32

    float* P_sum = (float*)d_ws;                             // 4*512*608 floats
    float* P_cnt = P_sum + (size_t)NIMG * NTILE * NSLOT;     // 4*512*19
    float* P_S2  = P_cnt + (size_t)NIMG * NTILE * NCLS;      // 4*512*19
    float* G     = P_S2  + (size_t)NIMG * NTILE * NCLS;      // 4*4*HWQ (1 MB)
    // all workspace slots fully overwritten every call -> no zeroing, no atomics

    k_gram <<<dim3(64, NIMG),    dim3(256),  0, stream>>>(E, G);
    k_field<<<dim3(NTILE, NIMG), dim3(256),  0, stream>>>(E, lab, G, P_sum, P_cnt, P_S2);
    k_final<<<dim3(NIMG),        dim3(1024), 0, stream>>>(P_sum, P_cnt, P_S2, out);
}